// Round 12
// baseline (79.669 us; speedup 1.0000x reference)
//
#include <hip/hip_runtime.h>
#include <cfloat>

typedef __bf16 bf16x8 __attribute__((ext_vector_type(8)));
typedef unsigned short ushort8 __attribute__((ext_vector_type(8)));
typedef float f32x16 __attribute__((ext_vector_type(16)));

#define S_SLICES 8   // 48 x 8 x 2 = 768 blocks = 3/CU exact at 12 waves/CU

// fp32 -> bf16 bits, round-to-nearest-even
static __device__ __forceinline__ unsigned short f2bf(float x) {
    unsigned u = __float_as_uint(x);
    return (unsigned short)((u + 0x7FFFu + ((u >> 16) & 1u)) >> 16);
}
static __device__ __forceinline__ float bfbits2f(unsigned short h) {
    return __uint_as_float(((unsigned)h) << 16);
}

// Per point, build TWO 16-element K-vectors (verified round 7/8):
//  row vec: [-2hx,-2hy,-2hz, -2hx,-2hy,-2hz, -2lx,-2ly,-2lz, s1,s2,s3, 1,1,1, 0]
//  col vec: [ hx,  hy,  hz,   lx,  ly,  lz,   hx,  hy,  hz,  1,1,1, t1,t2,t3, 0]
//  => sum_k row[k]*col[k] = nrmRow + nrmCol - 2(hh+hl+lh) ~= d2 (err ~1e-4).
// Fragment storage: frag[tile*64 + q*32 + l5], point = tile*32+l5, k = q*8+j.
// Pad points get nrm=1e30 -> never win a min.
__global__ __launch_bounds__(256) void prep_kernel(
    const float* __restrict__ A, const float* __restrict__ B,
    ushort8* __restrict__ RFA, ushort8* __restrict__ CFA,
    ushort8* __restrict__ RFB, ushort8* __restrict__ CFB,
    float* __restrict__ hdr, int n, int m, int RTn, int RTm)
{
    const int i = blockIdx.x * 256 + threadIdx.x;
    if (i < 8) hdr[i] = 0.f;
    const unsigned short one = 0x3F80;

#pragma unroll
    for (int side = 0; side < 2; ++side) {
        const int cntPts = side ? RTm * 32 : RTn * 32;
        if (i >= cntPts) continue;
        const float* P = side ? B : A;
        const int lim = side ? m : n;
        ushort8* RF = side ? RFB : RFA;
        ushort8* CF = side ? CFB : CFA;

        float x = 0.f, y = 0.f, z = 0.f, nrm = 1e30f;
        if (i < lim) { x = P[3*i]; y = P[3*i+1]; z = P[3*i+2];
                       nrm = fmaf(x, x, fmaf(y, y, z * z)); }
        const unsigned short hx = f2bf(x), hy = f2bf(y), hz = f2bf(z);
        const unsigned short lx = f2bf(x - bfbits2f(hx)),
                             ly = f2bf(y - bfbits2f(hy)),
                             lz = f2bf(z - bfbits2f(hz));
        const unsigned short nhx = f2bf(-2.f * bfbits2f(hx)),
                             nhy = f2bf(-2.f * bfbits2f(hy)),
                             nhz = f2bf(-2.f * bfbits2f(hz));
        const unsigned short nlx = f2bf(-2.f * bfbits2f(lx)),
                             nly = f2bf(-2.f * bfbits2f(ly)),
                             nlz = f2bf(-2.f * bfbits2f(lz));
        float r = nrm;
        const unsigned short s1 = f2bf(r); r -= bfbits2f(s1);
        const unsigned short s2 = f2bf(r); r -= bfbits2f(s2);
        const unsigned short s3 = f2bf(r);

        const int t = i >> 5, l5 = i & 31;
        ushort8 rq0 = { nhx, nhy, nhz, nhx, nhy, nhz, nlx, nly };
        ushort8 rq1 = { nlz, s1, s2, s3, one, one, one, 0 };
        RF[t * 64 + l5]      = rq0;
        RF[t * 64 + 32 + l5] = rq1;
        ushort8 cq0 = { hx, hy, hz, lx, ly, lz, hx, hy };
        ushort8 cq1 = { hz, one, one, one, s1, s2, s3, 0 };
        CF[t * 64 + l5]      = cq0;
        CF[t * 64 + 32 + l5] = cq1;
    }
}

#define MFMA(a, b) __builtin_amdgcn_mfma_f32_32x32x16_bf16((a), (b), zc, 0, 0, 0)
#define MIN0(C)                                             \
    _Pragma("unroll")                                       \
    for (int r = 0; r < 16; ++r) macc0[r] = fminf(macc0[r], (C)[r]);
#define MIN1(C)                                             \
    _Pragma("unroll")                                       \
    for (int r = 0; r < 16; ++r) macc1[r] = fminf(macc1[r], (C)[r]);

// z=0: rows=A vs cols=B -> sbuf side 0 ("mins"); z=1: transposed ("mins_seeds").
// One wave owns TWO row-tiles (64 rows): each b-load feeds 2 MFMAs + 32 fmins
// (round 11: 1 MFMA/load still ~3x over issue floor -> latency-bound; doubling
// compute-per-load halves the outstanding loads needed AND halves b traffic).
// __launch_bounds__(256,3): ~170-VGPR budget for 4 C tiles + 2 macc + queue
// in VGPRs (128 would re-trigger round-8's accvgpr shuttle).
__global__ __launch_bounds__(256, 3) void pairmin_kernel(
    const bf16x8* __restrict__ RFA, const bf16x8* __restrict__ CFA,
    const bf16x8* __restrict__ RFB, const bf16x8* __restrict__ CFB,
    float* __restrict__ sbuf, int RTn, int RTm)
{
    const int lane = threadIdx.x & 63;
    const int wave = threadIdx.x >> 6;

    const bf16x8* RF; const bf16x8* CF; float* sb; int rtCount, ctCount, stride;
    if (blockIdx.z == 0) { RF = RFA; CF = CFB; rtCount = RTn; ctCount = RTm;
                           sb = sbuf; stride = RTn * 32; }
    else                 { RF = RFB; CF = CFA; rtCount = RTm; ctCount = RTn;
                           sb = sbuf + (size_t)S_SLICES * RTn * 32;
                           stride = RTm * 32; }

    const int RTP = (rtCount + 1) >> 1;
    const int rtPair = blockIdx.x * 4 + wave;
    if (rtPair >= RTP) return;                       // wave-uniform
    const int rt0 = rtPair * 2;
    const int rt1 = min(rt0 + 1, rtCount - 1);       // clamp (dup is benign)
    sb += (size_t)blockIdx.y * stride;

    const int ctPer = (ctCount + S_SLICES - 1) / S_SLICES;
    const int ctBeg = min(blockIdx.y * ctPer, ctCount);
    const int ctEnd = min(ctBeg + ctPer, ctCount);

    const bf16x8 a0 = RF[rt0 * 64 + lane];           // loop-invariant
    const bf16x8 a1 = RF[rt1 * 64 + lane];
    const f32x16 zc = {};

    float macc0[16], macc1[16];
#pragma unroll
    for (int r = 0; r < 16; ++r) { macc0[r] = FLT_MAX; macc1[r] = FLT_MAX; }

    if (ctBeg < ctEnd) {
        int ct = ctBeg;
        const int last = ctEnd - 1;
        bf16x8 q0 = CF[(size_t)ct * 64 + lane];
        bf16x8 q1 = CF[(size_t)min(ct + 1, last) * 64 + lane];
        bf16x8 q2 = CF[(size_t)min(ct + 2, last) * 64 + lane];
        bf16x8 q3 = CF[(size_t)min(ct + 3, last) * 64 + lane];
        f32x16 C0a = MFMA(a0, q0), C0b = MFMA(a1, q0);
        f32x16 C1a = MFMA(a0, q1), C1b = MFMA(a1, q1);

        // steady state: 4 tiles/iter; invariant at top: C0=tile ct, C1=ct+1,
        // q2=ct+2, q3=ct+3.
        for (; ct + 7 < ctEnd; ct += 4) {
            q0 = CF[(size_t)(ct + 4) * 64 + lane];
            MIN0(C0a); MIN1(C0b);
            C0a = MFMA(a0, q2); C0b = MFMA(a1, q2);
            q1 = CF[(size_t)(ct + 5) * 64 + lane];
            MIN0(C1a); MIN1(C1b);
            C1a = MFMA(a0, q3); C1b = MFMA(a1, q3);
            q2 = CF[(size_t)(ct + 6) * 64 + lane];
            MIN0(C0a); MIN1(C0b);
            C0a = MFMA(a0, q0); C0b = MFMA(a1, q0);
            q3 = CF[(size_t)(ct + 7) * 64 + lane];
            MIN0(C1a); MIN1(C1b);
            C1a = MFMA(a0, q1); C1b = MFMA(a1, q1);
        }
        // epilogue: C0/C1 hold ct/ct+1 (clamped dups are min-idempotent)
        MIN0(C0a); MIN1(C0b);
        MIN0(C1a); MIN1(C1b);
        if (ct + 2 < ctEnd) {
            C0a = MFMA(a0, q2); C0b = MFMA(a1, q2);
            MIN0(C0a); MIN1(C0b);
        }
        if (ct + 3 < ctEnd) {
            C0a = MFMA(a0, q3); C0b = MFMA(a1, q3);
            MIN0(C0a); MIN1(C0b);
        }
        for (int t = ct + 4; t < ctEnd; ++t) {
            const bf16x8 b = CF[(size_t)t * 64 + lane];
            C0a = MFMA(a0, b); C0b = MFMA(a1, b);
            MIN0(C0a); MIN1(C0b);
        }
    }

    // reduce row mins across the 32 cols held in each 32-lane half
#pragma unroll
    for (int r = 0; r < 16; ++r) {
        float v = macc0[r], w = macc1[r];
        v = fminf(v, __shfl_xor(v, 1, 64));  w = fminf(w, __shfl_xor(w, 1, 64));
        v = fminf(v, __shfl_xor(v, 2, 64));  w = fminf(w, __shfl_xor(w, 2, 64));
        v = fminf(v, __shfl_xor(v, 4, 64));  w = fminf(w, __shfl_xor(w, 4, 64));
        v = fminf(v, __shfl_xor(v, 8, 64));  w = fminf(w, __shfl_xor(w, 8, 64));
        v = fminf(v, __shfl_xor(v, 16, 64)); w = fminf(w, __shfl_xor(w, 16, 64));
        macc0[r] = v; macc1[r] = w;
    }
    if ((lane & 31) == 0) {
        const int q4 = (lane >> 5) * 4;              // C map: row=(r&3)+8*(r>>2)+4*q
        float* dst0 = sb + rt0 * 32;
        float* dst1 = sb + rt1 * 32;
#pragma unroll
        for (int r = 0; r < 16; ++r) {
            const int row = (r & 3) + 8 * (r >> 2) + q4;
            dst0[row] = macc0[r];
            dst1[row] = macc1[r];
        }
    }
}

// out layout: [loss+loss_seeds, mins_seeds(m), loss, loss_seeds]
__global__ __launch_bounds__(256) void finalize_kernel(
    const float* __restrict__ sbuf, float* __restrict__ hdr,
    float* __restrict__ out, int n, int m, int RTn, int RTm)
{
    const int i = blockIdx.x * 256 + threadIdx.x;
    const int strideA = RTn * 32, strideB = RTm * 32;
    const float* sbB = sbuf + (size_t)S_SLICES * strideA;

    float sa = 0.f, sb_ = 0.f;
    if (i < n) {
        float s = FLT_MAX;
#pragma unroll
        for (int k = 0; k < S_SLICES; ++k) s = fminf(s, sbuf[(size_t)k * strideA + i]);
        sa = sqrtf(fmaxf(s, 0.f));
    }
    if (i < m) {
        float s = FLT_MAX;
#pragma unroll
        for (int k = 0; k < S_SLICES; ++k) s = fminf(s, sbB[(size_t)k * strideB + i]);
        const float v = sqrtf(fmaxf(s, 0.f));
        out[1 + i] = v;                  // mins_seeds
        sb_ = v;
    }

#pragma unroll
    for (int off = 32; off > 0; off >>= 1) {
        sa  += __shfl_down(sa,  off, 64);
        sb_ += __shfl_down(sb_, off, 64);
    }
    __shared__ float reda[4], redb[4];
    const int wave = threadIdx.x >> 6;
    const int lane = threadIdx.x & 63;
    if (lane == 0) { reda[wave] = sa; redb[wave] = sb_; }
    __syncthreads();

    if (threadIdx.x == 0) {
        const float ta = reda[0] + reda[1] + reda[2] + reda[3];
        const float tb = redb[0] + redb[1] + redb[2] + redb[3];
        atomicAdd(&hdr[0], ta);
        atomicAdd(&hdr[1], tb);
        __threadfence();
        const unsigned ticket = atomicAdd((unsigned*)&hdr[2], 1u);
        if (ticket == (unsigned)(gridDim.x - 1)) {
            const float fa = atomicAdd(&hdr[0], 0.f);
            const float fb = atomicAdd(&hdr[1], 0.f);
            const float loss = fa / (float)n;
            const float loss_seeds = fb / (float)m;
            out[0] = loss + loss_seeds;
            out[1 + m] = loss;
            out[2 + m] = loss_seeds;
        }
    }
}

extern "C" void kernel_launch(void* const* d_in, const int* in_sizes, int n_in,
                              void* d_out, int out_size, void* d_ws, size_t ws_size,
                              hipStream_t stream) {
    const int n = in_sizes[0] / 3;   // true_pos count
    const int m = in_sizes[1] / 3;   // pred_pos count
    const float* A = (const float*)d_in[0];
    const float* B = (const float*)d_in[1];
    float* out = (float*)d_out;

    const int RTn = (n + 31) / 32, RTm = (m + 31) / 32;
    char* p = (char*)d_ws;
    float*   hdr  = (float*)p;    p += 64;
    float*   sbuf = (float*)p;    p += (size_t)S_SLICES * (RTn + RTm) * 32 * 4;
    ushort8* RFA  = (ushort8*)p;  p += (size_t)RTn * 64 * 16;
    ushort8* CFA  = (ushort8*)p;  p += (size_t)RTn * 64 * 16;
    ushort8* RFB  = (ushort8*)p;  p += (size_t)RTm * 64 * 16;
    ushort8* CFB  = (ushort8*)p;

    const int maxPts = ((RTn > RTm) ? RTn : RTm) * 32;
    prep_kernel<<<(maxPts + 255) / 256, 256, 0, stream>>>(
        A, B, RFA, CFA, RFB, CFB, hdr, n, m, RTn, RTm);

    const int maxRT = (RTn > RTm) ? RTn : RTm;
    const int maxRTP = (maxRT + 1) / 2;
    dim3 grid((maxRTP + 3) / 4, S_SLICES, 2);
    pairmin_kernel<<<grid, 256, 0, stream>>>(
        (const bf16x8*)RFA, (const bf16x8*)CFA,
        (const bf16x8*)RFB, (const bf16x8*)CFB, sbuf, RTn, RTm);

    const int maxnm = (n > m) ? n : m;
    finalize_kernel<<<(maxnm + 255) / 256, 256, 0, stream>>>(
        sbuf, hdr, out, n, m, RTn, RTm);
}